// Round 4
// baseline (419.506 us; speedup 1.0000x reference)
//
#include <hip/hip_runtime.h>
#include <cstdint>
#include <cstddef>

#define HIDDEN 256
#define NHEADS 8
#define HDIM 32
#define KLEN 8192
#define BATCH 32
#define NCHUNK_S 64
#define CROWS (KLEN / NCHUNK_S)   // 128
#define NSPLIT 8
#define LN_EPS 1e-5f

// ---------------- workspace layout (float offsets) ----------------
#define OFF_QT    ((size_t)0)
#define SZ_QT     ((size_t)2*BATCH*NHEADS*HIDDEN)           // 131072
#define OFF_SC    (OFF_QT + SZ_QT)
#define SZ_SC     ((size_t)2*BATCH*KLEN*NHEADS)             // 4194304
#define OFF_UP    (OFF_SC + SZ_SC)
#define SZ_UP     ((size_t)2*BATCH*NSPLIT*NHEADS*HIDDEN)    // 1048576
#define OFF_COMB  (OFF_UP + SZ_UP)
#define SZ_COMB   ((size_t)BATCH*2*HIDDEN)                  // 16384
#define OFF_SLIST (OFF_COMB + SZ_COMB)
#define SZ_SLIST  ((size_t)2*BATCH*KLEN)                    // 524288 (ints)
#define OFF_SCNT  (OFF_SLIST + SZ_SLIST)
#define SZ_SCNT   ((size_t)2*BATCH)

// K1: qh = z_gene @ Wq^T, then qtilde[m][b][n][h] = alpha * sum_d qh[n,d]*Wk_m[n*32+d, h]
__global__ void k_prep(const float* __restrict__ zg, const float* __restrict__ Wq,
                       const float* __restrict__ Wk0, const float* __restrict__ Wk1,
                       const float* __restrict__ log_temp, float* __restrict__ qt) {
    int b = blockIdx.x, t = threadIdx.x;
    __shared__ float z[HIDDEN];
    __shared__ float qh[HIDDEN];
    z[t] = zg[(size_t)b*HIDDEN + t];
    __syncthreads();
    const float4* wr4 = (const float4*)(Wq + (size_t)t*HIDDEN);
    const float4* z4 = (const float4*)z;
    float acc = 0.f;
    #pragma unroll 8
    for (int i = 0; i < HIDDEN/4; ++i) {
        float4 w = wr4[i], zz = z4[i];
        acc += w.x*zz.x + w.y*zz.y + w.z*zz.z + w.w*zz.w;
    }
    qh[t] = acc;
    __syncthreads();
    float alpha = 0.5f * rsqrtf((float)HDIM) * __expf(log_temp[0]);
    for (int m = 0; m < 2; ++m) {
        const float* Wk = m ? Wk1 : Wk0;
        for (int n = 0; n < NHEADS; ++n) {
            float a = 0.f;
            #pragma unroll 8
            for (int d = 0; d < HDIM; ++d) {
                a += qh[n*HDIM + d] * Wk[(size_t)(n*HDIM + d)*HIDDEN + t];
            }
            qt[(((size_t)m*BATCH + b)*NHEADS + n)*HIDDEN + t] = a * alpha;
        }
    }
}

// K2 v4: deep-pipelined scores. 8-lane group handles 4 rows; 16 float4 loads
// kept in flight via 4 static-indexed buffers (no vmcnt(0) drain per i-iter).
__global__ void __launch_bounds__(256, 4) k_scores(const float* __restrict__ kv0,
                                                   const float* __restrict__ kv1,
                                                   const float* __restrict__ qt,
                                                   float* __restrict__ sc) {
    int bid = blockIdx.x;              // BATCH * 2 * NCHUNK_S = 4096
    int chunk = bid % NCHUNK_S;
    int m = (bid / NCHUNK_S) & 1;
    int b = bid / (2*NCHUNK_S);
    int t = threadIdx.x;
    int gg  = t >> 3;                  // group 0..31
    int seg = t & 7;
    __shared__ float lq[NHEADS*260];   // padded stride 260
    const float* qtg = qt + ((size_t)m*BATCH + b)*NHEADS*HIDDEN;
    #pragma unroll
    for (int i = 0; i < 8; ++i) {
        int j = t + i*256;
        lq[(j >> 8)*260 + (j & 255)] = qtg[j];
    }
    __syncthreads();
    const float* kv = (m ? kv1 : kv0) + (size_t)b*KLEN*HIDDEN;
    const float4* kv4 = (const float4*)kv;
    float* out = sc + ((size_t)m*BATCH + b)*KLEN*NHEADS;
    int b0 = seg & 1, b1 = (seg >> 1) & 1, b2 = (seg >> 2) & 1;

    size_t r = (size_t)chunk*CROWS + gg*4;
    const float4* row0 = kv4 + (r+0)*64;
    const float4* row1 = kv4 + (r+1)*64;
    const float4* row2 = kv4 + (r+2)*64;
    const float4* row3 = kv4 + (r+3)*64;

    float acc[4][8];
    #pragma unroll
    for (int j = 0; j < 4; ++j)
        #pragma unroll
        for (int n = 0; n < 8; ++n) acc[j][n] = 0.f;

    float4 A0,A1,A2,A3, B0,B1,B2,B3, C0,C1,C2,C3, D0,D1,D2,D3;
    #define LOADQ(R0,R1,R2,R3,i) { int c = (i)*8 + seg; \
        R0 = row0[c]; R1 = row1[c]; R2 = row2[c]; R3 = row3[c]; }
    #define FMAQ(R0,R1,R2,R3,i) { int c = (i)*8 + seg; \
        _Pragma("unroll") \
        for (int n = 0; n < 8; ++n) { \
            float4 q = ((const float4*)(lq + n*260))[c]; \
            acc[0][n] += R0.x*q.x + R0.y*q.y + R0.z*q.z + R0.w*q.w; \
            acc[1][n] += R1.x*q.x + R1.y*q.y + R1.z*q.z + R1.w*q.w; \
            acc[2][n] += R2.x*q.x + R2.y*q.y + R2.z*q.z + R2.w*q.w; \
            acc[3][n] += R3.x*q.x + R3.y*q.y + R3.z*q.z + R3.w*q.w; } }

    LOADQ(A0,A1,A2,A3,0)
    LOADQ(B0,B1,B2,B3,1)
    LOADQ(C0,C1,C2,C3,2)
    LOADQ(D0,D1,D2,D3,3)
    FMAQ(A0,A1,A2,A3,0) LOADQ(A0,A1,A2,A3,4)
    FMAQ(B0,B1,B2,B3,1) LOADQ(B0,B1,B2,B3,5)
    FMAQ(C0,C1,C2,C3,2) LOADQ(C0,C1,C2,C3,6)
    FMAQ(D0,D1,D2,D3,3) LOADQ(D0,D1,D2,D3,7)
    FMAQ(A0,A1,A2,A3,4)
    FMAQ(B0,B1,B2,B3,5)
    FMAQ(C0,C1,C2,C3,6)
    FMAQ(D0,D1,D2,D3,7)
    #undef LOADQ
    #undef FMAQ

    #pragma unroll
    for (int j = 0; j < 4; ++j) {
        float w[4];
        #pragma unroll
        for (int u = 0; u < 4; ++u) {
            float kkeep = b0 ? acc[j][2*u+1] : acc[j][2*u];
            float ksend = b0 ? acc[j][2*u]   : acc[j][2*u+1];
            w[u] = kkeep + __shfl_xor(ksend, 1);
        }
        float x[2];
        #pragma unroll
        for (int u = 0; u < 2; ++u) {
            float kkeep = b1 ? w[2*u+1] : w[2*u];
            float ksend = b1 ? w[2*u]   : w[2*u+1];
            x[u] = kkeep + __shfl_xor(ksend, 2);
        }
        float kkeep = b2 ? x[1] : x[0];
        float ksend = b2 ? x[0] : x[1];
        float y = kkeep + __shfl_xor(ksend, 4);
        out[(r+j)*8 + seg] = y;
    }
}

// K3: entmax tau by bisection, then write p = max(z-tau,0)^2 back into sc (own column)
__global__ void __launch_bounds__(256) k_entmax(float* __restrict__ sc) {
    int bid = blockIdx.x;              // m*256 + b*8 + n
    int n = bid & 7, b = (bid >> 3) & 31, m = bid >> 8;
    int t = threadIdx.x;
    __shared__ float zs[KLEN];
    __shared__ float red[4];
    float* src = sc + ((size_t)m*BATCH + b)*KLEN*NHEADS + n;
    float mx = -1e30f;
    #pragma unroll
    for (int i = 0; i < KLEN/256; ++i) {
        float v = src[(size_t)(t + i*256)*NHEADS];
        zs[t + i*256] = v;
        mx = fmaxf(mx, v);
    }
    for (int off = 32; off; off >>= 1) mx = fmaxf(mx, __shfl_xor(mx, off));
    if ((t & 63) == 0) red[t >> 6] = mx;
    __syncthreads();
    mx = fmaxf(fmaxf(red[0], red[1]), fmaxf(red[2], red[3]));
    __syncthreads();
    const float4* z4 = (const float4*)zs;
    float lo = mx - 1.0f, hi = mx;
    for (int it = 0; it < 26; ++it) {
        float tm = 0.5f*(lo + hi);
        float s = 0.f;
        #pragma unroll
        for (int i = 0; i < 8; ++i) {
            float4 zz = z4[t + i*256];
            float d;
            d = fmaxf(zz.x - tm, 0.f); s = fmaf(d, d, s);
            d = fmaxf(zz.y - tm, 0.f); s = fmaf(d, d, s);
            d = fmaxf(zz.z - tm, 0.f); s = fmaf(d, d, s);
            d = fmaxf(zz.w - tm, 0.f); s = fmaf(d, d, s);
        }
        for (int off = 32; off; off >>= 1) s += __shfl_xor(s, off);
        if ((t & 63) == 0) red[t >> 6] = s;
        __syncthreads();
        s = red[0] + red[1] + red[2] + red[3];
        __syncthreads();
        if (s >= 1.0f) lo = tm; else hi = tm;
    }
    float tfin = 0.5f*(lo + hi);
    #pragma unroll
    for (int i = 0; i < KLEN/256; ++i) {
        float d = fmaxf(zs[t + i*256] - tfin, 0.f);
        src[(size_t)(t + i*256)*NHEADS] = d*d;
    }
}

// K3b: build compacted support-row list per (m,b): rows where any head's p > 0.
// Deterministic (ballot + prefix, no atomics); ascending row order.
__global__ void __launch_bounds__(256) k_support(const float* __restrict__ sc,
                                                 int* __restrict__ slist,
                                                 int* __restrict__ scnt) {
    int mb = blockIdx.x;               // 0..63
    int t = threadIdx.x;
    int lane = t & 63, w = t >> 6;
    __shared__ int wcnt[4];
    const float4* p4 = (const float4*)(sc + (size_t)mb*KLEN*NHEADS);
    int* list = slist + (size_t)mb*KLEN;
    int base = 0;
    for (int i = 0; i < KLEN/256; ++i) {
        int k = i*256 + t;
        float4 pa = p4[(size_t)k*2];
        float4 pb = p4[(size_t)k*2 + 1];
        float mxp = fmaxf(fmaxf(fmaxf(pa.x, pa.y), fmaxf(pa.z, pa.w)),
                          fmaxf(fmaxf(pb.x, pb.y), fmaxf(pb.z, pb.w)));
        bool f = (mxp > 0.f);
        unsigned long long mask = __ballot(f);
        if (lane == 0) wcnt[w] = __popcll(mask);
        __syncthreads();
        int wbase = base;
        #pragma unroll
        for (int wi = 0; wi < 4; ++wi) if (wi < w) wbase += wcnt[wi];
        if (f) list[wbase + __popcll(mask & ((1ull << lane) - 1ull))] = k;
        base += wcnt[0] + wcnt[1] + wcnt[2] + wcnt[3];
        __syncthreads();
    }
    if (t == 0) scnt[mb] = base;
}

// K4 v5: sparse context sum — gather only support rows.
// Block (m,b,s): waves take list entries j = s + NSPLIT*w + NSPLIT*4*iter.
// Lane owns float4 column = lane; p broadcast-loaded per row.
__global__ void __launch_bounds__(256) k_ctxsum(const float* __restrict__ kv0,
                                                const float* __restrict__ kv1,
                                                const float* __restrict__ sc,
                                                const int* __restrict__ slist,
                                                const int* __restrict__ scnt,
                                                float* __restrict__ upart) {
    int bid = blockIdx.x;              // 2*BATCH*NSPLIT = 512
    int s = bid % NSPLIT;
    int mb = bid / NSPLIT;             // m*32+b
    int t = threadIdx.x;
    int wave = t >> 6, lane = t & 63;
    const float* kv = ((mb >> 5) ? kv1 : kv0) + (size_t)(mb & 31)*KLEN*HIDDEN;
    const float4* kv4 = (const float4*)kv;
    const float4* p4 = (const float4*)(sc + (size_t)mb*KLEN*NHEADS);
    const int* list = slist + (size_t)mb*KLEN;
    int cnt = scnt[mb];
    float acc[8][4];
    #pragma unroll
    for (int nn = 0; nn < 8; ++nn)
        #pragma unroll
        for (int c = 0; c < 4; ++c) acc[nn][c] = 0.f;

    for (int j = s + NSPLIT*wave; j < cnt; j += NSPLIT*4) {
        int k = list[j];
        float4 kvv = kv4[(size_t)k*64 + lane];
        float4 p0 = p4[(size_t)k*2];
        float4 p1 = p4[(size_t)k*2 + 1];
        acc[0][0] = fmaf(p0.x, kvv.x, acc[0][0]); acc[0][1] = fmaf(p0.x, kvv.y, acc[0][1]);
        acc[0][2] = fmaf(p0.x, kvv.z, acc[0][2]); acc[0][3] = fmaf(p0.x, kvv.w, acc[0][3]);
        acc[1][0] = fmaf(p0.y, kvv.x, acc[1][0]); acc[1][1] = fmaf(p0.y, kvv.y, acc[1][1]);
        acc[1][2] = fmaf(p0.y, kvv.z, acc[1][2]); acc[1][3] = fmaf(p0.y, kvv.w, acc[1][3]);
        acc[2][0] = fmaf(p0.z, kvv.x, acc[2][0]); acc[2][1] = fmaf(p0.z, kvv.y, acc[2][1]);
        acc[2][2] = fmaf(p0.z, kvv.z, acc[2][2]); acc[2][3] = fmaf(p0.z, kvv.w, acc[2][3]);
        acc[3][0] = fmaf(p0.w, kvv.x, acc[3][0]); acc[3][1] = fmaf(p0.w, kvv.y, acc[3][1]);
        acc[3][2] = fmaf(p0.w, kvv.z, acc[3][2]); acc[3][3] = fmaf(p0.w, kvv.w, acc[3][3]);
        acc[4][0] = fmaf(p1.x, kvv.x, acc[4][0]); acc[4][1] = fmaf(p1.x, kvv.y, acc[4][1]);
        acc[4][2] = fmaf(p1.x, kvv.z, acc[4][2]); acc[4][3] = fmaf(p1.x, kvv.w, acc[4][3]);
        acc[5][0] = fmaf(p1.y, kvv.x, acc[5][0]); acc[5][1] = fmaf(p1.y, kvv.y, acc[5][1]);
        acc[5][2] = fmaf(p1.y, kvv.z, acc[5][2]); acc[5][3] = fmaf(p1.y, kvv.w, acc[5][3]);
        acc[6][0] = fmaf(p1.z, kvv.x, acc[6][0]); acc[6][1] = fmaf(p1.z, kvv.y, acc[6][1]);
        acc[6][2] = fmaf(p1.z, kvv.z, acc[6][2]); acc[6][3] = fmaf(p1.z, kvv.w, acc[6][3]);
        acc[7][0] = fmaf(p1.w, kvv.x, acc[7][0]); acc[7][1] = fmaf(p1.w, kvv.y, acc[7][1]);
        acc[7][2] = fmaf(p1.w, kvv.z, acc[7][2]); acc[7][3] = fmaf(p1.w, kvv.w, acc[7][3]);
    }
    // cross-wave reduce via LDS
    __shared__ float redls[4*NHEADS*HIDDEN];    // 32 KB
    float4* red4 = (float4*)redls;
    #pragma unroll
    for (int nn = 0; nn < 8; ++nn) {
        float4 v; v.x = acc[nn][0]; v.y = acc[nn][1]; v.z = acc[nn][2]; v.w = acc[nn][3];
        red4[((size_t)wave*8 + nn)*64 + lane] = v;
    }
    __syncthreads();
    float* up = upart + ((size_t)mb*NSPLIT + s)*NHEADS*HIDDEN;
    int n = t >> 5, hq = (t & 31)*2;
    #pragma unroll
    for (int j = 0; j < 2; ++j) {
        float4 sum = red4[((size_t)0*8 + n)*64 + hq + j];
        #pragma unroll
        for (int w = 1; w < 4; ++w) {
            float4 v = red4[((size_t)w*8 + n)*64 + hq + j];
            sum.x += v.x; sum.y += v.y; sum.z += v.z; sum.w += v.w;
        }
        ((float4*)(up + (size_t)n*HIDDEN))[hq + j] = sum;
    }
}

// K5: reduce splits, project through Wv, apply modality softmax weight
__global__ void k_ctx(const float* __restrict__ upart, const float* __restrict__ Wv0,
                      const float* __restrict__ Wv1, const float* __restrict__ mlogits,
                      float* __restrict__ comb) {
    int b = blockIdx.x, t = threadIdx.x;
    __shared__ float ul[NHEADS*260];
    float l0 = mlogits[0], l1 = mlogits[1];
    float mxl = fmaxf(l0, l1);
    float e0 = __expf(l0 - mxl), e1 = __expf(l1 - mxl);
    float w0 = e0/(e0 + e1), w1 = e1/(e0 + e1);
    for (int m = 0; m < 2; ++m) {
        const float* Wv = m ? Wv1 : Wv0;
        float wm = m ? w1 : w0;
        __syncthreads();
        for (int n = 0; n < NHEADS; ++n) {
            float s = 0.f;
            const float* up = upart + ((size_t)m*BATCH + b)*NSPLIT*NHEADS*HIDDEN
                              + (size_t)n*HIDDEN + t;
            #pragma unroll
            for (int c = 0; c < NSPLIT; ++c) s += up[(size_t)c*NHEADS*HIDDEN];
            ul[n*260 + t] = s;
        }
        __syncthreads();
        int n = t >> 5;   // t = n*32 + d
        const float4* wr4 = (const float4*)(Wv + (size_t)t*HIDDEN);
        const float4* uu4 = (const float4*)(ul + n*260);
        float acc = 0.f;
        #pragma unroll 8
        for (int i = 0; i < HIDDEN/4; ++i) {
            float4 w = wr4[i], uu = uu4[i];
            acc += w.x*uu.x + w.y*uu.y + w.z*uu.z + w.w*uu.w;
        }
        comb[(size_t)b*(2*HIDDEN) + (size_t)m*HIDDEN + t] = acc * wm;
    }
}

// K6: out = LayerNorm(comb @ Wout^T + b_out + z_gene)
__global__ void k_out(const float* __restrict__ comb, const float* __restrict__ Wout,
                      const float* __restrict__ bout, const float* __restrict__ zg,
                      const float* __restrict__ gamma, const float* __restrict__ beta,
                      float* __restrict__ out) {
    int b = blockIdx.x, t = threadIdx.x;
    __shared__ float cl[2*HIDDEN];
    __shared__ float red[4];
    cl[t] = comb[(size_t)b*512 + t];
    cl[t + 256] = comb[(size_t)b*512 + 256 + t];
    __syncthreads();
    float acc = bout[t] + zg[(size_t)b*HIDDEN + t];
    const float4* wr4 = (const float4*)(Wout + (size_t)t*512);
    const float4* cl4 = (const float4*)cl;
    #pragma unroll 8
    for (int i = 0; i < 512/4; ++i) {
        float4 w = wr4[i], c = cl4[i];
        acc += w.x*c.x + w.y*c.y + w.z*c.z + w.w*c.w;
    }
    float s = acc;
    for (int off = 32; off; off >>= 1) s += __shfl_xor(s, off);
    if ((t & 63) == 0) red[t >> 6] = s;
    __syncthreads();
    float mu = (red[0] + red[1] + red[2] + red[3]) * (1.0f/HIDDEN);
    __syncthreads();
    float dv = acc - mu;
    float vs = dv*dv;
    for (int off = 32; off; off >>= 1) vs += __shfl_xor(vs, off);
    if ((t & 63) == 0) red[t >> 6] = vs;
    __syncthreads();
    float var = (red[0] + red[1] + red[2] + red[3]) * (1.0f/HIDDEN);
    out[(size_t)b*HIDDEN + t] = dv * rsqrtf(var + LN_EPS) * gamma[t] + beta[t];
}

extern "C" void kernel_launch(void* const* d_in, const int* in_sizes, int n_in,
                              void* d_out, int out_size, void* d_ws, size_t ws_size,
                              hipStream_t stream) {
    const float* zg    = (const float*)d_in[0];
    const float* cpg   = (const float*)d_in[1];
    const float* mir   = (const float*)d_in[2];
    const float* Wq    = (const float*)d_in[3];
    const float* Wk0   = (const float*)d_in[4];
    const float* Wv0   = (const float*)d_in[5];
    const float* Wk1   = (const float*)d_in[6];
    const float* Wv1   = (const float*)d_in[7];
    const float* Wout  = (const float*)d_in[8];
    const float* bout  = (const float*)d_in[9];
    const float* gam   = (const float*)d_in[10];
    const float* bet   = (const float*)d_in[11];
    const float* mlog  = (const float*)d_in[12];
    const float* ltemp = (const float*)d_in[13];

    float* ws    = (float*)d_ws;
    float* qt    = ws + OFF_QT;
    float* sc    = ws + OFF_SC;
    float* up    = ws + OFF_UP;
    float* comb  = ws + OFF_COMB;
    int*   slist = (int*)(ws + OFF_SLIST);
    int*   scnt  = (int*)(ws + OFF_SCNT);
    float* out   = (float*)d_out;

    hipLaunchKernelGGL(k_prep,    dim3(BATCH),             dim3(256), 0, stream,
                       zg, Wq, Wk0, Wk1, ltemp, qt);
    hipLaunchKernelGGL(k_scores,  dim3(BATCH*2*NCHUNK_S),  dim3(256), 0, stream,
                       cpg, mir, qt, sc);
    hipLaunchKernelGGL(k_entmax,  dim3(2*BATCH*NHEADS),    dim3(256), 0, stream,
                       sc);
    hipLaunchKernelGGL(k_support, dim3(2*BATCH),           dim3(256), 0, stream,
                       sc, slist, scnt);
    hipLaunchKernelGGL(k_ctxsum,  dim3(2*BATCH*NSPLIT),    dim3(256), 0, stream,
                       cpg, mir, sc, slist, scnt, up);
    hipLaunchKernelGGL(k_ctx,     dim3(BATCH),             dim3(256), 0, stream,
                       up, Wv0, Wv1, mlog, comb);
    hipLaunchKernelGGL(k_out,     dim3(BATCH),             dim3(256), 0, stream,
                       comb, Wout, bout, zg, gam, bet, out);
}

// Round 5
// 349.505 us; speedup vs baseline: 1.2003x; 1.2003x over previous
//
#include <hip/hip_runtime.h>
#include <hip/hip_bf16.h>
#include <cstdint>
#include <cstddef>

#define HIDDEN 256
#define NHEADS 8
#define HDIM 32
#define KLEN 8192
#define BATCH 32
#define NSPLIT 16
#define LN_EPS 1e-5f

typedef __attribute__((ext_vector_type(8))) short bf16x8;
typedef __attribute__((ext_vector_type(4))) float f32x4;

// ---------------- workspace layout (float offsets) ----------------
#define OFF_QT    ((size_t)0)
#define SZ_QT     ((size_t)2*BATCH*NHEADS*HIDDEN)           // 131072
#define OFF_SC    (OFF_QT + SZ_QT)
#define SZ_SC     ((size_t)2*BATCH*KLEN*NHEADS)             // 4194304
#define OFF_UP    (OFF_SC + SZ_SC)
#define SZ_UP     ((size_t)2*BATCH*NSPLIT*NHEADS*HIDDEN)    // 2097152
#define OFF_COMB  (OFF_UP + SZ_UP)
#define SZ_COMB   ((size_t)BATCH*2*HIDDEN)                  // 16384

static __device__ inline short f2b(float f) {
    __hip_bfloat16 h = __float2bfloat16(f);
    return (short)__builtin_bit_cast(unsigned short, h);
}

// K1: qh = z_gene @ Wq^T, then qtilde[m][b][n][h] = alpha * sum_d qh[n,d]*Wk_m[n*32+d, h]
__global__ void k_prep(const float* __restrict__ zg, const float* __restrict__ Wq,
                       const float* __restrict__ Wk0, const float* __restrict__ Wk1,
                       const float* __restrict__ log_temp, float* __restrict__ qt) {
    int b = blockIdx.x, t = threadIdx.x;
    __shared__ float z[HIDDEN];
    __shared__ float qh[HIDDEN];
    z[t] = zg[(size_t)b*HIDDEN + t];
    __syncthreads();
    const float4* wr4 = (const float4*)(Wq + (size_t)t*HIDDEN);
    const float4* z4 = (const float4*)z;
    float acc = 0.f;
    #pragma unroll 8
    for (int i = 0; i < HIDDEN/4; ++i) {
        float4 w = wr4[i], zz = z4[i];
        acc += w.x*zz.x + w.y*zz.y + w.z*zz.z + w.w*zz.w;
    }
    qh[t] = acc;
    __syncthreads();
    float alpha = 0.5f * rsqrtf((float)HDIM) * __expf(log_temp[0]);
    for (int m = 0; m < 2; ++m) {
        const float* Wk = m ? Wk1 : Wk0;
        for (int n = 0; n < NHEADS; ++n) {
            float a = 0.f;
            #pragma unroll 8
            for (int d = 0; d < HDIM; ++d) {
                a += qh[n*HDIM + d] * Wk[(size_t)(n*HDIM + d)*HIDDEN + t];
            }
            qt[(((size_t)m*BATCH + b)*NHEADS + n)*HIDDEN + t] = a * alpha;
        }
    }
}

// K2 v5: MFMA scores. Per wave: 16-row tiles of kv; A-frag lane l holds
// kv[R+(l&15)][c*32+(l>>4)*8+j] (2 float4 loads per chunk, 16 in flight).
// B-frag = qtilde (heads in cols 0-7, cols 8-15 duplicated/unused).
// C: col=lane&15, row=(lane>>4)*4+reg.
__global__ void __launch_bounds__(256, 3) k_scores(const float* __restrict__ kv0,
                                                   const float* __restrict__ kv1,
                                                   const float* __restrict__ qt,
                                                   float* __restrict__ sc) {
    int bid = blockIdx.x;              // 64 mb * 32 slabs = 2048
    int slab = bid & 31;
    int mb = bid >> 5;                 // m*32+b
    int t = threadIdx.x;
    int wave = t >> 6, l = t & 63;
    int row16 = l & 15, kgrp = l >> 4;
    const float* kv = ((mb >> 5) ? kv1 : kv0) + (size_t)(mb & 31)*KLEN*HIDDEN;

    // B-frags: q̃ for this (m,b); lane needs head=(l&15)&7, k=c*32+kgrp*8+j
    const float* qb = qt + (size_t)mb*NHEADS*HIDDEN + (size_t)((l & 15) & 7)*HIDDEN + kgrp*8;
    bf16x8 fq[8];
    #pragma unroll
    for (int c = 0; c < 8; ++c) {
        float4 qa = *(const float4*)(qb + c*32);
        float4 qc = *(const float4*)(qb + c*32 + 4);
        bf16x8 q;
        q[0] = f2b(qa.x); q[1] = f2b(qa.y); q[2] = f2b(qa.z); q[3] = f2b(qa.w);
        q[4] = f2b(qc.x); q[5] = f2b(qc.y); q[6] = f2b(qc.z); q[7] = f2b(qc.w);
        fq[c] = q;
    }
    float* out = sc + (size_t)mb*KLEN*NHEADS;
    int rbase = slab*256 + wave*64;

    for (int tt = 0; tt < 4; ++tt) {
        int R = rbase + tt*16;
        const float* ptr = kv + (size_t)(R + row16)*HIDDEN + kgrp*8;
        float4 va[8], vb[8];
        #pragma unroll
        for (int c = 0; c < 8; ++c) {
            va[c] = *(const float4*)(ptr + c*32);
            vb[c] = *(const float4*)(ptr + c*32 + 4);
        }
        f32x4 acc = {0.f, 0.f, 0.f, 0.f};
        #pragma unroll
        for (int c = 0; c < 8; ++c) {
            bf16x8 a;
            a[0] = f2b(va[c].x); a[1] = f2b(va[c].y); a[2] = f2b(va[c].z); a[3] = f2b(va[c].w);
            a[4] = f2b(vb[c].x); a[5] = f2b(vb[c].y); a[6] = f2b(vb[c].z); a[7] = f2b(vb[c].w);
            acc = __builtin_amdgcn_mfma_f32_16x16x32_bf16(a, fq[c], acc, 0, 0, 0);
        }
        if ((l & 15) < 8) {
            int col = l & 15;
            #pragma unroll
            for (int r = 0; r < 4; ++r) {
                out[(size_t)(R + kgrp*4 + r)*NHEADS + col] = acc[r];
            }
        }
    }
}

// K3: entmax tau by bisection, then write p = max(z-tau,0)^2 back into sc (own column)
__global__ void __launch_bounds__(256) k_entmax(float* __restrict__ sc) {
    int bid = blockIdx.x;              // m*256 + b*8 + n
    int n = bid & 7, b = (bid >> 3) & 31, m = bid >> 8;
    int t = threadIdx.x;
    __shared__ float zs[KLEN];
    __shared__ float red[4];
    float* src = sc + ((size_t)m*BATCH + b)*KLEN*NHEADS + n;
    float mx = -1e30f;
    #pragma unroll
    for (int i = 0; i < KLEN/256; ++i) {
        float v = src[(size_t)(t + i*256)*NHEADS];
        zs[t + i*256] = v;
        mx = fmaxf(mx, v);
    }
    for (int off = 32; off; off >>= 1) mx = fmaxf(mx, __shfl_xor(mx, off));
    if ((t & 63) == 0) red[t >> 6] = mx;
    __syncthreads();
    mx = fmaxf(fmaxf(red[0], red[1]), fmaxf(red[2], red[3]));
    __syncthreads();
    const float4* z4 = (const float4*)zs;
    float lo = mx - 1.0f, hi = mx;
    for (int it = 0; it < 26; ++it) {
        float tm = 0.5f*(lo + hi);
        float s = 0.f;
        #pragma unroll
        for (int i = 0; i < 8; ++i) {
            float4 zz = z4[t + i*256];
            float d;
            d = fmaxf(zz.x - tm, 0.f); s = fmaf(d, d, s);
            d = fmaxf(zz.y - tm, 0.f); s = fmaf(d, d, s);
            d = fmaxf(zz.z - tm, 0.f); s = fmaf(d, d, s);
            d = fmaxf(zz.w - tm, 0.f); s = fmaf(d, d, s);
        }
        for (int off = 32; off; off >>= 1) s += __shfl_xor(s, off);
        if ((t & 63) == 0) red[t >> 6] = s;
        __syncthreads();
        s = red[0] + red[1] + red[2] + red[3];
        __syncthreads();
        if (s >= 1.0f) lo = tm; else hi = tm;
    }
    float tfin = 0.5f*(lo + hi);
    #pragma unroll
    for (int i = 0; i < KLEN/256; ++i) {
        float d = fmaxf(zs[t + i*256] - tfin, 0.f);
        src[(size_t)(t + i*256)*NHEADS] = d*d;
    }
}

// K4 v6: MFMA context sum. C[n][h-slice] = sum_k p[k][n] * kv[k][h].
// A-frag = p^T (4B scattered loads of L2-resident sc);
// B-frag = kv[k][h] via 4B loads — each 128B line covers two adjacent ct
// tiles and is consumed immediately, so kv streams at full-line granularity.
// 16 f32x4 accumulators (one per 16-col tile). Reverse block order for L3.
__global__ void __launch_bounds__(256, 3) k_ctxsum(const float* __restrict__ kv0,
                                                   const float* __restrict__ kv1,
                                                   const float* __restrict__ sc,
                                                   float* __restrict__ upart) {
    int rb = (int)gridDim.x - 1 - (int)blockIdx.x;
    int s = rb & (NSPLIT - 1);
    int mb = rb / NSPLIT;              // m*32+b
    int t = threadIdx.x;
    int wave = t >> 6, l = t & 63;
    int col16 = l & 15, kgrp = l >> 4;
    int hn = col16 & 7;
    const float* kv = ((mb >> 5) ? kv1 : kv0) + (size_t)(mb & 31)*KLEN*HIDDEN;
    const float* pbase = sc + (size_t)mb*KLEN*NHEADS;

    f32x4 accs[16];
    #pragma unroll
    for (int ct = 0; ct < 16; ++ct) accs[ct] = (f32x4){0.f, 0.f, 0.f, 0.f};

    int kbase = s*512 + wave*128;
    for (int kc = 0; kc < 4; ++kc) {
        int k0 = kbase + kc*32 + kgrp*8;
        // A-frag: p[k0+j][hn]
        float pf[8];
        #pragma unroll
        for (int j = 0; j < 8; ++j) pf[j] = pbase[(size_t)(k0 + j)*NHEADS + hn];
        bf16x8 afrag;
        afrag[0] = f2b(pf[0]); afrag[1] = f2b(pf[1]); afrag[2] = f2b(pf[2]); afrag[3] = f2b(pf[3]);
        afrag[4] = f2b(pf[4]); afrag[5] = f2b(pf[5]); afrag[6] = f2b(pf[6]); afrag[7] = f2b(pf[7]);
        const float* brow = kv + (size_t)k0*HIDDEN + col16;
        #pragma unroll
        for (int ct = 0; ct < 16; ++ct) {
            float bf[8];
            #pragma unroll
            for (int j = 0; j < 8; ++j) bf[j] = brow[(size_t)j*HIDDEN + ct*16];
            bf16x8 bfrag;
            bfrag[0] = f2b(bf[0]); bfrag[1] = f2b(bf[1]); bfrag[2] = f2b(bf[2]); bfrag[3] = f2b(bf[3]);
            bfrag[4] = f2b(bf[4]); bfrag[5] = f2b(bf[5]); bfrag[6] = f2b(bf[6]); bfrag[7] = f2b(bf[7]);
            accs[ct] = __builtin_amdgcn_mfma_f32_16x16x32_bf16(afrag, bfrag, accs[ct], 0, 0, 0);
        }
    }
    // per-block reduce: rows 0-7 live in lanes with kgrp<2 (row = kgrp*4+r)
    __shared__ float redls[4*NHEADS*HIDDEN];    // 32 KB
    if (kgrp < 2) {
        #pragma unroll
        for (int ct = 0; ct < 16; ++ct) {
            #pragma unroll
            for (int r = 0; r < 4; ++r) {
                int row = kgrp*4 + r;
                redls[((size_t)wave*NHEADS + row)*HIDDEN + ct*16 + col16] = accs[ct][r];
            }
        }
    }
    __syncthreads();
    float* up = upart + ((size_t)mb*NSPLIT + s)*NHEADS*HIDDEN;
    float4* red4 = (float4*)redls;
    int n = t >> 5, hq = (t & 31)*2;
    #pragma unroll
    for (int j = 0; j < 2; ++j) {
        float4 sum = red4[((size_t)0*NHEADS + n)*64 + hq + j];
        #pragma unroll
        for (int w = 1; w < 4; ++w) {
            float4 v = red4[((size_t)w*NHEADS + n)*64 + hq + j];
            sum.x += v.x; sum.y += v.y; sum.z += v.z; sum.w += v.w;
        }
        ((float4*)(up + (size_t)n*HIDDEN))[hq + j] = sum;
    }
}

// K5: reduce splits, project through Wv, apply modality softmax weight
__global__ void k_ctx(const float* __restrict__ upart, const float* __restrict__ Wv0,
                      const float* __restrict__ Wv1, const float* __restrict__ mlogits,
                      float* __restrict__ comb) {
    int b = blockIdx.x, t = threadIdx.x;
    __shared__ float ul[NHEADS*260];
    float l0 = mlogits[0], l1 = mlogits[1];
    float mxl = fmaxf(l0, l1);
    float e0 = __expf(l0 - mxl), e1 = __expf(l1 - mxl);
    float w0 = e0/(e0 + e1), w1 = e1/(e0 + e1);
    for (int m = 0; m < 2; ++m) {
        const float* Wv = m ? Wv1 : Wv0;
        float wm = m ? w1 : w0;
        __syncthreads();
        for (int n = 0; n < NHEADS; ++n) {
            float s = 0.f;
            const float* up = upart + ((size_t)m*BATCH + b)*NSPLIT*NHEADS*HIDDEN
                              + (size_t)n*HIDDEN + t;
            #pragma unroll
            for (int c = 0; c < NSPLIT; ++c) s += up[(size_t)c*NHEADS*HIDDEN];
            ul[n*260 + t] = s;
        }
        __syncthreads();
        int n = t >> 5;   // t = n*32 + d
        const float4* wr4 = (const float4*)(Wv + (size_t)t*HIDDEN);
        const float4* uu4 = (const float4*)(ul + n*260);
        float acc = 0.f;
        #pragma unroll 8
        for (int i = 0; i < HIDDEN/4; ++i) {
            float4 w = wr4[i], uu = uu4[i];
            acc += w.x*uu.x + w.y*uu.y + w.z*uu.z + w.w*uu.w;
        }
        comb[(size_t)b*(2*HIDDEN) + (size_t)m*HIDDEN + t] = acc * wm;
    }
}

// K6: out = LayerNorm(comb @ Wout^T + b_out + z_gene)
__global__ void k_out(const float* __restrict__ comb, const float* __restrict__ Wout,
                      const float* __restrict__ bout, const float* __restrict__ zg,
                      const float* __restrict__ gamma, const float* __restrict__ beta,
                      float* __restrict__ out) {
    int b = blockIdx.x, t = threadIdx.x;
    __shared__ float cl[2*HIDDEN];
    __shared__ float red[4];
    cl[t] = comb[(size_t)b*512 + t];
    cl[t + 256] = comb[(size_t)b*512 + 256 + t];
    __syncthreads();
    float acc = bout[t] + zg[(size_t)b*HIDDEN + t];
    const float4* wr4 = (const float4*)(Wout + (size_t)t*512);
    const float4* cl4 = (const float4*)cl;
    #pragma unroll 8
    for (int i = 0; i < 512/4; ++i) {
        float4 w = wr4[i], c = cl4[i];
        acc += w.x*c.x + w.y*c.y + w.z*c.z + w.w*c.w;
    }
    float s = acc;
    for (int off = 32; off; off >>= 1) s += __shfl_xor(s, off);
    if ((t & 63) == 0) red[t >> 6] = s;
    __syncthreads();
    float mu = (red[0] + red[1] + red[2] + red[3]) * (1.0f/HIDDEN);
    __syncthreads();
    float dv = acc - mu;
    float vs = dv*dv;
    for (int off = 32; off; off >>= 1) vs += __shfl_xor(vs, off);
    if ((t & 63) == 0) red[t >> 6] = vs;
    __syncthreads();
    float var = (red[0] + red[1] + red[2] + red[3]) * (1.0f/HIDDEN);
    out[(size_t)b*HIDDEN + t] = dv * rsqrtf(var + LN_EPS) * gamma[t] + beta[t];
}

extern "C" void kernel_launch(void* const* d_in, const int* in_sizes, int n_in,
                              void* d_out, int out_size, void* d_ws, size_t ws_size,
                              hipStream_t stream) {
    const float* zg    = (const float*)d_in[0];
    const float* cpg   = (const float*)d_in[1];
    const float* mir   = (const float*)d_in[2];
    const float* Wq    = (const float*)d_in[3];
    const float* Wk0   = (const float*)d_in[4];
    const float* Wv0   = (const float*)d_in[5];
    const float* Wk1   = (const float*)d_in[6];
    const float* Wv1   = (const float*)d_in[7];
    const float* Wout  = (const float*)d_in[8];
    const float* bout  = (const float*)d_in[9];
    const float* gam   = (const float*)d_in[10];
    const float* bet   = (const float*)d_in[11];
    const float* mlog  = (const float*)d_in[12];
    const float* ltemp = (const float*)d_in[13];

    float* ws    = (float*)d_ws;
    float* qt    = ws + OFF_QT;
    float* sc    = ws + OFF_SC;
    float* up    = ws + OFF_UP;
    float* comb  = ws + OFF_COMB;
    float* out   = (float*)d_out;

    hipLaunchKernelGGL(k_prep,    dim3(BATCH),            dim3(256), 0, stream,
                       zg, Wq, Wk0, Wk1, ltemp, qt);
    hipLaunchKernelGGL(k_scores,  dim3(2*BATCH*32),       dim3(256), 0, stream,
                       cpg, mir, qt, sc);
    hipLaunchKernelGGL(k_entmax,  dim3(2*BATCH*NHEADS),   dim3(256), 0, stream,
                       sc);
    hipLaunchKernelGGL(k_ctxsum,  dim3(2*BATCH*NSPLIT),   dim3(256), 0, stream,
                       cpg, mir, sc, up);
    hipLaunchKernelGGL(k_ctx,     dim3(BATCH),            dim3(256), 0, stream,
                       up, Wv0, Wv1, mlog, comb);
    hipLaunchKernelGGL(k_out,     dim3(BATCH),            dim3(256), 0, stream,
                       comb, Wout, bout, zg, gam, bet, out);
}